// Round 1
// baseline (1815.355 us; speedup 1.0000x reference)
//
#include <hip/hip_runtime.h>
#include <math.h>

// LocalSelfAttention2d: B=4, CIN=HC=256, H=W=128, P=8, heads=8, dh=32
// pad = 8 total (4/4) -> 136x136 padded, 17x17 windows of 64 positions.
//
// Round 1: correct fp32 baseline.
//  K1: per (b,window) block: stage x-tile in LDS, loop heads:
//      QKV projection (GEMM vs wave-uniform weight rows) -> LDS q/k/v
//      -> 64x64 attention (scaled softmax incl. zero-padding keys) -> o image in ws.
//  K2: per 8x8 output tile: stage o-tile, GEMM vs w_out, add bias, write cropped y.

#define CIN   256
#define HC    256
#define NHEAD 8
#define DH    32
#define PWIN  8
#define HIMG  128
#define WIMG  128
#define PADO  4
#define HPAD  136
#define WPAD  136
#define NWROW 17
#define NWIN  289
#define PP    64
#define ATT_SCALE 0.17677669529663687f  // 1/sqrt(32)

__global__ __launch_bounds__(512, 1)
void lsa_qkv_attn(const float* __restrict__ x,
                  const float* __restrict__ wqkv,
                  const float* __restrict__ bqkv,
                  const float* __restrict__ posb,
                  float* __restrict__ oimg)
{
    __shared__ float xs[CIN][PP];        // 64 KB  x tile, [channel][pos]
    __shared__ float qs[PP][DH + 4];     // 9 KB   stride 36 floats = 144B (16B aligned, spreads banks)
    __shared__ float ks[PP][DH + 4];
    __shared__ float vs[PP][DH + 4];
    __shared__ float Sm[PP][PP + 1];     // 16.25 KB  scores / probs
    __shared__ float rs[PP];             // row sums

    const int t    = threadIdx.x;
    const int wv   = t >> 6;
    const int lane = t & 63;
    const int bx   = blockIdx.x;
    const int b    = bx / NWIN;
    const int win  = bx - b * NWIN;
    const int wi   = win / NWROW;
    const int wj   = win - wi * NWROW;
    const int hbase = wi * PWIN - PADO;
    const int wbase = wj * PWIN - PADO;

    // ---- stage x tile (zeros outside image) ----
    #pragma unroll 4
    for (int i = 0; i < 32; ++i) {
        int n = (i << 9) + t;
        int c = n >> 6;
        int p = n & 63;
        int h = hbase + (p >> 3);
        int w = wbase + (p & 7);
        float v = 0.0f;
        if ((unsigned)h < (unsigned)HIMG && (unsigned)w < (unsigned)WIMG)
            v = x[(((size_t)b * CIN + c) * HIMG + h) * WIMG + w];
        xs[c][p] = v;
    }
    __syncthreads();

    const int hp = wi * PWIN + (lane >> 3);
    const int wp = wj * PWIN + (lane & 7);

    for (int head = 0; head < NHEAD; ++head) {
        // ---- QKV projection: 96 outputs (q0..31,k0..31,v0..31) x 64 pos, K=256.
        // lane = position; wave wv owns outputs m = wv*12 .. wv*12+11 (wave-uniform rows).
        float acc[12];
        #pragma unroll
        for (int j = 0; j < 12; ++j) acc[j] = 0.0f;

        const int mbase = __builtin_amdgcn_readfirstlane(wv * 12);
        const float* wr[12];
        #pragma unroll
        for (int j = 0; j < 12; ++j) {
            int m = mbase + j;
            int sect = m >> 5;
            int d = m & 31;
            wr[j] = wqkv + (size_t)(sect * HC + head * DH + d) * CIN;
        }
        for (int k0 = 0; k0 < CIN; k0 += 4) {
            float xv0 = xs[k0 + 0][lane];
            float xv1 = xs[k0 + 1][lane];
            float xv2 = xs[k0 + 2][lane];
            float xv3 = xs[k0 + 3][lane];
            #pragma unroll
            for (int j = 0; j < 12; ++j) {
                float4 w4 = *reinterpret_cast<const float4*>(wr[j] + k0);
                acc[j] = fmaf(xv0, w4.x, acc[j]);
                acc[j] = fmaf(xv1, w4.y, acc[j]);
                acc[j] = fmaf(xv2, w4.z, acc[j]);
                acc[j] = fmaf(xv3, w4.w, acc[j]);
            }
        }

        __syncthreads();  // previous head's PV finished reading vs/Sm/rs

        #pragma unroll
        for (int j = 0; j < 12; ++j) {
            int m = mbase + j;
            int sect = m >> 5;
            int d = m & 31;
            int o = sect * HC + head * DH + d;
            float v = acc[j] + bqkv[o];
            if (sect == 0) {
                // learned position bias added to q only
                v += posb[(size_t)(head * DH + d) * PP + lane];
                qs[lane][d] = v;
            } else if (sect == 1) {
                ks[lane][d] = v;
            } else {
                vs[lane][d] = v;
            }
        }
        __syncthreads();

        // ---- S = scale * Q K^T : r = lane, c = wv*8+i ----
        {
            float sacc[8];
            #pragma unroll
            for (int i = 0; i < 8; ++i) sacc[i] = 0.0f;
            #pragma unroll
            for (int k0 = 0; k0 < DH; k0 += 4) {
                float4 q4 = *reinterpret_cast<const float4*>(&qs[lane][k0]);
                #pragma unroll
                for (int i = 0; i < 8; ++i) {
                    float4 k4 = *reinterpret_cast<const float4*>(&ks[(wv << 3) + i][k0]);
                    sacc[i] = fmaf(q4.x, k4.x, sacc[i]);
                    sacc[i] = fmaf(q4.y, k4.y, sacc[i]);
                    sacc[i] = fmaf(q4.z, k4.z, sacc[i]);
                    sacc[i] = fmaf(q4.w, k4.w, sacc[i]);
                }
            }
            #pragma unroll
            for (int i = 0; i < 8; ++i) Sm[lane][(wv << 3) + i] = sacc[i] * ATT_SCALE;
        }
        __syncthreads();

        // ---- softmax over 64 cols: 8 threads per row ----
        {
            const int r = t >> 3;
            const int g = t & 7;
            float vals[8];
            float mx = -1e30f;
            #pragma unroll
            for (int i = 0; i < 8; ++i) {
                vals[i] = Sm[r][(g << 3) + i];
                mx = fmaxf(mx, vals[i]);
            }
            mx = fmaxf(mx, __shfl_xor(mx, 1));
            mx = fmaxf(mx, __shfl_xor(mx, 2));
            mx = fmaxf(mx, __shfl_xor(mx, 4));
            float sum = 0.0f;
            #pragma unroll
            for (int i = 0; i < 8; ++i) {
                vals[i] = __expf(vals[i] - mx);
                sum += vals[i];
            }
            sum += __shfl_xor(sum, 1);
            sum += __shfl_xor(sum, 2);
            sum += __shfl_xor(sum, 4);
            #pragma unroll
            for (int i = 0; i < 8; ++i) Sm[r][(g << 3) + i] = vals[i];
            if (g == 0) rs[r] = sum;
        }
        __syncthreads();

        // ---- O = P V (unnormalized) then divide by row sum; write o image ----
        {
            const int d0 = wv << 2;
            float oacc[4];
            #pragma unroll
            for (int i = 0; i < 4; ++i) oacc[i] = 0.0f;
            for (int c = 0; c < PP; ++c) {
                float pv = Sm[lane][c];
                float4 v4 = *reinterpret_cast<const float4*>(&vs[c][d0]);
                oacc[0] = fmaf(pv, v4.x, oacc[0]);
                oacc[1] = fmaf(pv, v4.y, oacc[1]);
                oacc[2] = fmaf(pv, v4.z, oacc[2]);
                oacc[3] = fmaf(pv, v4.w, oacc[3]);
            }
            float rinv = 1.0f / rs[lane];
            #pragma unroll
            for (int i = 0; i < 4; ++i) {
                int cch = head * DH + d0 + i;
                oimg[(((size_t)b * HC + cch) * HPAD + hp) * WPAD + wp] = oacc[i] * rinv;
            }
        }
        // next head's barrier (before qs/ks/vs writes) protects vs/Sm/rs
    }
}

__global__ __launch_bounds__(512, 1)
void lsa_out(const float* __restrict__ oimg,
             const float* __restrict__ wout,
             const float* __restrict__ bout,
             float* __restrict__ y)
{
    __shared__ float os[HC][PP];  // 64 KB

    const int t    = threadIdx.x;
    const int wv   = t >> 6;
    const int lane = t & 63;
    const int bx   = blockIdx.x;
    const int b    = bx >> 8;
    const int h0   = ((bx >> 4) & 15) << 3;
    const int w0   = (bx & 15) << 3;

    #pragma unroll 4
    for (int i = 0; i < 32; ++i) {
        int n = (i << 9) + t;
        int c = n >> 6;
        int p = n & 63;
        os[c][p] = oimg[(((size_t)b * HC + c) * HPAD + (h0 + (p >> 3) + PADO)) * WPAD
                        + (w0 + (p & 7) + PADO)];
    }
    __syncthreads();

    const int hh = h0 + (lane >> 3);
    const int ww = w0 + (lane & 7);

    #pragma unroll
    for (int pass = 0; pass < 2; ++pass) {
        const int mb = __builtin_amdgcn_readfirstlane(wv * 32 + pass * 16);
        float acc[16];
        #pragma unroll
        for (int j = 0; j < 16; ++j) acc[j] = 0.0f;
        for (int k0 = 0; k0 < HC; k0 += 4) {
            float xv0 = os[k0 + 0][lane];
            float xv1 = os[k0 + 1][lane];
            float xv2 = os[k0 + 2][lane];
            float xv3 = os[k0 + 3][lane];
            #pragma unroll
            for (int j = 0; j < 16; ++j) {
                float4 w4 = *reinterpret_cast<const float4*>(wout + (size_t)(mb + j) * HC + k0);
                acc[j] = fmaf(xv0, w4.x, acc[j]);
                acc[j] = fmaf(xv1, w4.y, acc[j]);
                acc[j] = fmaf(xv2, w4.z, acc[j]);
                acc[j] = fmaf(xv3, w4.w, acc[j]);
            }
        }
        #pragma unroll
        for (int j = 0; j < 16; ++j) {
            int co = mb + j;
            y[(((size_t)b * HC + co) * HIMG + hh) * WIMG + ww] = acc[j] + bout[co];
        }
    }
}

extern "C" void kernel_launch(void* const* d_in, const int* in_sizes, int n_in,
                              void* d_out, int out_size, void* d_ws, size_t ws_size,
                              hipStream_t stream)
{
    const float* x    = (const float*)d_in[0];
    const float* wqkv = (const float*)d_in[1];
    const float* bqkv = (const float*)d_in[2];
    const float* posb = (const float*)d_in[3];
    const float* wout = (const float*)d_in[4];
    const float* bout = (const float*)d_in[5];
    float* out  = (float*)d_out;
    float* oimg = (float*)d_ws;  // 4*256*136*136 f32 = 75.8 MB, fully rewritten every call

    lsa_qkv_attn<<<dim3(4 * NWIN), dim3(512), 0, stream>>>(x, wqkv, bqkv, posb, oimg);
    lsa_out<<<dim3(4 * 256), dim3(512), 0, stream>>>(oimg, wout, bout, out);
}

// Round 2
// 213.543 us; speedup vs baseline: 8.5011x; 8.5011x over previous
//
#include <hip/hip_runtime.h>

// LocalSelfAttention2d fused MFMA implementation for gfx950.
// B=4, CIN=HC=256, heads=8, dh=32, P=8, img 128x128, pad 4/4 -> 136x136, 17x17 windows.
//
// K0: convert w_qkv (768x256) and w_out (256x256) fp32 -> bf16 into d_ws.
// K1 (fused, block = (b,win), 8 waves, wave = head):
//   phase0: stage x window-tile as bf16 in LDS xs[64 pos][264 ch-stride]
//   phase1: QKV GEMM via mfma_f32_16x16x32_bf16; epilogue -> per-wave LDS q/k/vT
//   phase2: attention per wave: S=mfma(K,Q), in-reg softmax, P via private LDS,
//           O^T=mfma(vT,P), normalize, write o -> LDS os[pos][ch] (overlays xs)
//   phase3: out-proj GEMM + bias + crop -> y

typedef __attribute__((ext_vector_type(8))) short bf16x8;
typedef __attribute__((ext_vector_type(4))) float f32x4;

#define CIN   256
#define NWROW 17
#define NWIN  289
#define PADO  4
#define HIMG  128
#define ATT_SCALE 0.17677669529663687f  // 1/sqrt(32)

// LDS geometry (ushort units)
#define XS_STRIDE 264                       // 528 B rows: 16B aligned, 2-way max on frag reads
#define XS_SIZE   (64 * XS_STRIDE)          // 16896
#define QK_STRIDE 40                        // 80 B rows (16B aligned)
#define VT_STRIDE 72                        // 144 B rows (16B aligned)
#define P_STRIDE  72
#define WREG_Q    0
#define WREG_K    (64 * QK_STRIDE)          // 2560
#define WREG_VT   (2 * 64 * QK_STRIDE)      // 5120  (P overlays [0..4608) < 5120)
#define WREG_SIZE (WREG_VT + 32 * VT_STRIDE) // 7424 ush = 14848 B per wave
#define LDS_USH   (XS_SIZE + 8 * WREG_SIZE)  // 76288 ush = 152576 B

__device__ __forceinline__ ushort f2bf(float f) {
    unsigned u = __float_as_uint(f);
    u += 0x7FFFu + ((u >> 16) & 1u);   // RNE
    return (ushort)(u >> 16);
}
__device__ __forceinline__ unsigned pack2(float a, float b) {
    return (unsigned)f2bf(a) | ((unsigned)f2bf(b) << 16);
}

__global__ void lsa_wconv(const float* __restrict__ wqkv,
                          const float* __restrict__ wout,
                          ushort* __restrict__ dst)
{
    int n = blockIdx.x * 256 + threadIdx.x;   // 1024 blocks x 256 = 262144
    float v = (n < 196608) ? wqkv[n] : wout[n - 196608];
    dst[n] = f2bf(v);
}

__global__ __launch_bounds__(512, 2)
void lsa_fused(const float* __restrict__ x,
               const float* __restrict__ bqkv,
               const float* __restrict__ posb,
               const float* __restrict__ bout,
               const ushort* __restrict__ wqkvb,
               const ushort* __restrict__ woutb,
               float* __restrict__ y)
{
    __shared__ __align__(16) ushort sm[LDS_USH];

    const int t    = threadIdx.x;
    const int wv   = t >> 6;        // wave index == head
    const int lane = t & 63;
    const int g    = lane >> 4;     // lane group 0..3
    const int c    = lane & 15;     // lane col 0..15
    const int bx   = blockIdx.x;
    const int b    = bx / NWIN;
    const int win  = bx - b * NWIN;
    const int wi   = win / NWROW;
    const int wj   = win - wi * NWROW;
    const int hbase = wi * 8 - PADO;
    const int wbase = wj * 8 - PADO;

    // ---------------- phase 0: stage x tile (bf16, [pos][ch]) ----------------
    #pragma unroll 4
    for (int i = 0; i < 32; ++i) {
        int n  = (i << 9) + t;
        int ch = n >> 6;
        int p  = n & 63;
        int h  = hbase + (p >> 3);
        int w  = wbase + (p & 7);
        float v = 0.0f;
        if ((unsigned)h < (unsigned)HIMG && (unsigned)w < (unsigned)HIMG)
            v = x[(((size_t)b * CIN + ch) * HIMG + h) * HIMG + w];
        sm[p * XS_STRIDE + ch] = f2bf(v);
    }
    __syncthreads();

    ushort* wreg = &sm[XS_SIZE + wv * WREG_SIZE];

    // ---------------- phase 1: QKV GEMM for head wv ----------------
    // m-tiles: s6 = sect*2 + mt, sect 0=q 1=k 2=v; m0 = sect*256 + wv*32 + mt*16
    f32x4 acc[6][4];
    #pragma unroll
    for (int i = 0; i < 6; ++i)
        #pragma unroll
        for (int j = 0; j < 4; ++j)
            acc[i][j] = (f32x4){0.f, 0.f, 0.f, 0.f};

    const ushort* wrow[6];
    #pragma unroll
    for (int s6 = 0; s6 < 6; ++s6) {
        int m0 = (s6 >> 1) * 256 + wv * 32 + (s6 & 1) * 16;
        wrow[s6] = wqkvb + (size_t)(m0 + c) * CIN;
    }

    #pragma unroll
    for (int ks = 0; ks < 8; ++ks) {
        bf16x8 bfr[4];
        #pragma unroll
        for (int pt = 0; pt < 4; ++pt)
            bfr[pt] = *(const bf16x8*)&sm[(pt * 16 + c) * XS_STRIDE + ks * 32 + 8 * g];
        #pragma unroll
        for (int s6 = 0; s6 < 6; ++s6) {
            bf16x8 afr = *(const bf16x8*)(wrow[s6] + ks * 32 + 8 * g);
            #pragma unroll
            for (int pt = 0; pt < 4; ++pt)
                acc[s6][pt] = __builtin_amdgcn_mfma_f32_16x16x32_bf16(afr, bfr[pt], acc[s6][pt], 0, 0, 0);
        }
    }

    // epilogue: bias (+posbias, scale for q) -> per-wave LDS q/k/vT
    #pragma unroll
    for (int s6 = 0; s6 < 6; ++s6) {
        const int sect = s6 >> 1;
        const int mt   = s6 & 1;
        const int m0   = sect * 256 + wv * 32 + mt * 16;
        f32x4 bq = *(const f32x4*)&bqkv[m0 + 4 * g];
        #pragma unroll
        for (int pt = 0; pt < 4; ++pt) {
            const int pos = pt * 16 + c;
            f32x4 a = acc[s6][pt];
            if (sect == 0) {
                float v0 = (a[0] + bq[0] + posb[(m0 + 4 * g + 0) * 64 + pos]) * ATT_SCALE;
                float v1 = (a[1] + bq[1] + posb[(m0 + 4 * g + 1) * 64 + pos]) * ATT_SCALE;
                float v2 = (a[2] + bq[2] + posb[(m0 + 4 * g + 2) * 64 + pos]) * ATT_SCALE;
                float v3 = (a[3] + bq[3] + posb[(m0 + 4 * g + 3) * 64 + pos]) * ATT_SCALE;
                unsigned w01 = pack2(v0, v1), w23 = pack2(v2, v3);
                *(unsigned*)&wreg[WREG_Q + pos * QK_STRIDE + mt * 16 + 4 * g]     = w01;
                *(unsigned*)&wreg[WREG_Q + pos * QK_STRIDE + mt * 16 + 4 * g + 2] = w23;
            } else if (sect == 1) {
                unsigned w01 = pack2(a[0] + bq[0], a[1] + bq[1]);
                unsigned w23 = pack2(a[2] + bq[2], a[3] + bq[3]);
                *(unsigned*)&wreg[WREG_K + pos * QK_STRIDE + mt * 16 + 4 * g]     = w01;
                *(unsigned*)&wreg[WREG_K + pos * QK_STRIDE + mt * 16 + 4 * g + 2] = w23;
            } else {
                #pragma unroll
                for (int r = 0; r < 4; ++r)
                    wreg[WREG_VT + (mt * 16 + 4 * g + r) * VT_STRIDE + pos] = f2bf(a[r] + bq[r]);
            }
        }
    }
    __syncthreads();   // all waves finished reading xs (os will overlay it)

    // ---------------- phase 2: attention (per-wave private) ----------------
    bf16x8 kf[4], qf[4];
    #pragma unroll
    for (int kt = 0; kt < 4; ++kt)
        kf[kt] = *(const bf16x8*)&wreg[WREG_K + (kt * 16 + c) * QK_STRIDE + 8 * g];
    #pragma unroll
    for (int qt = 0; qt < 4; ++qt)
        qf[qt] = *(const bf16x8*)&wreg[WREG_Q + (qt * 16 + c) * QK_STRIDE + 8 * g];

    f32x4 s[4][4];   // [kt][qt]: D rows = key (kt*16+4g+r), col = query (qt*16+c)
    #pragma unroll
    for (int kt = 0; kt < 4; ++kt)
        #pragma unroll
        for (int qt = 0; qt < 4; ++qt)
            s[kt][qt] = __builtin_amdgcn_mfma_f32_16x16x32_bf16(kf[kt], qf[qt],
                                                                (f32x4){0.f, 0.f, 0.f, 0.f}, 0, 0, 0);

    float rsum[4];
    #pragma unroll
    for (int qt = 0; qt < 4; ++qt) {
        float mx = s[0][qt][0];
        #pragma unroll
        for (int kt = 0; kt < 4; ++kt)
            #pragma unroll
            for (int r = 0; r < 4; ++r)
                mx = fmaxf(mx, s[kt][qt][r]);
        mx = fmaxf(mx, __shfl_xor(mx, 16));
        mx = fmaxf(mx, __shfl_xor(mx, 32));
        float sum = 0.f;
        float e[4][4];
        #pragma unroll
        for (int kt = 0; kt < 4; ++kt)
            #pragma unroll
            for (int r = 0; r < 4; ++r) {
                e[kt][r] = __expf(s[kt][qt][r] - mx);
                sum += e[kt][r];
            }
        sum += __shfl_xor(sum, 16);
        sum += __shfl_xor(sum, 32);
        rsum[qt] = 1.0f / sum;
        // write P row (q = qt*16+c), keys kt*16+4g+0..3  (overlays q/k region)
        #pragma unroll
        for (int kt = 0; kt < 4; ++kt) {
            unsigned w01 = pack2(e[kt][0], e[kt][1]);
            unsigned w23 = pack2(e[kt][2], e[kt][3]);
            *(unsigned*)&wreg[(qt * 16 + c) * P_STRIDE + kt * 16 + 4 * g]     = w01;
            *(unsigned*)&wreg[(qt * 16 + c) * P_STRIDE + kt * 16 + 4 * g + 2] = w23;
        }
    }

    // PV: O^T[d][q] = vT x P
    bf16x8 vf[2][2], pf[4][2];
    #pragma unroll
    for (int dt = 0; dt < 2; ++dt)
        #pragma unroll
        for (int k2 = 0; k2 < 2; ++k2)
            vf[dt][k2] = *(const bf16x8*)&wreg[WREG_VT + (dt * 16 + c) * VT_STRIDE + k2 * 32 + 8 * g];
    #pragma unroll
    for (int qt = 0; qt < 4; ++qt)
        #pragma unroll
        for (int k2 = 0; k2 < 2; ++k2)
            pf[qt][k2] = *(const bf16x8*)&wreg[(qt * 16 + c) * P_STRIDE + k2 * 32 + 8 * g];

    f32x4 o[2][4];
    #pragma unroll
    for (int dt = 0; dt < 2; ++dt)
        #pragma unroll
        for (int qt = 0; qt < 4; ++qt)
            o[dt][qt] = (f32x4){0.f, 0.f, 0.f, 0.f};
    #pragma unroll
    for (int k2 = 0; k2 < 2; ++k2)
        #pragma unroll
        for (int dt = 0; dt < 2; ++dt)
            #pragma unroll
            for (int qt = 0; qt < 4; ++qt)
                o[dt][qt] = __builtin_amdgcn_mfma_f32_16x16x32_bf16(vf[dt][k2], pf[qt][k2], o[dt][qt], 0, 0, 0);

    // normalize + write o -> os[pos][ch] (overlays xs)
    #pragma unroll
    for (int dt = 0; dt < 2; ++dt)
        #pragma unroll
        for (int qt = 0; qt < 4; ++qt) {
            const int pos = qt * 16 + c;
            const int ch0 = wv * 32 + dt * 16 + 4 * g;
            float rv = rsum[qt];
            unsigned w01 = pack2(o[dt][qt][0] * rv, o[dt][qt][1] * rv);
            unsigned w23 = pack2(o[dt][qt][2] * rv, o[dt][qt][3] * rv);
            *(unsigned*)&sm[pos * XS_STRIDE + ch0]     = w01;
            *(unsigned*)&sm[pos * XS_STRIDE + ch0 + 2] = w23;
        }
    __syncthreads();   // os complete

    // ---------------- phase 3: out projection ----------------
    f32x4 ya[2][4];
    #pragma unroll
    for (int i = 0; i < 2; ++i)
        #pragma unroll
        for (int j = 0; j < 4; ++j)
            ya[i][j] = (f32x4){0.f, 0.f, 0.f, 0.f};

    const ushort* worow[2];
    #pragma unroll
    for (int mt = 0; mt < 2; ++mt)
        worow[mt] = woutb + (size_t)(wv * 32 + mt * 16 + c) * 256;

    #pragma unroll
    for (int ks = 0; ks < 8; ++ks) {
        bf16x8 ofr[4];
        #pragma unroll
        for (int pt = 0; pt < 4; ++pt)
            ofr[pt] = *(const bf16x8*)&sm[(pt * 16 + c) * XS_STRIDE + ks * 32 + 8 * g];
        #pragma unroll
        for (int mt = 0; mt < 2; ++mt) {
            bf16x8 afr = *(const bf16x8*)(worow[mt] + ks * 32 + 8 * g);
            #pragma unroll
            for (int pt = 0; pt < 4; ++pt)
                ya[mt][pt] = __builtin_amdgcn_mfma_f32_16x16x32_bf16(afr, ofr[pt], ya[mt][pt], 0, 0, 0);
        }
    }

    // epilogue: bias + crop + store
    #pragma unroll
    for (int mt = 0; mt < 2; ++mt) {
        const int co0 = wv * 32 + mt * 16 + 4 * g;
        f32x4 bo = *(const f32x4*)&bout[co0];
        #pragma unroll
        for (int pt = 0; pt < 4; ++pt) {
            const int pos = pt * 16 + c;
            const int hh = wi * 8 + (pos >> 3) - PADO;
            const int ww = wj * 8 + (pos & 7) - PADO;
            if ((unsigned)hh < (unsigned)HIMG && (unsigned)ww < (unsigned)HIMG) {
                #pragma unroll
                for (int r = 0; r < 4; ++r)
                    y[(((size_t)b * 256 + co0 + r) * HIMG + hh) * HIMG + ww] = ya[mt][pt][r] + bo[r];
            }
        }
    }
}

extern "C" void kernel_launch(void* const* d_in, const int* in_sizes, int n_in,
                              void* d_out, int out_size, void* d_ws, size_t ws_size,
                              hipStream_t stream)
{
    const float* x    = (const float*)d_in[0];
    const float* wqkv = (const float*)d_in[1];
    const float* bqkv = (const float*)d_in[2];
    const float* posb = (const float*)d_in[3];
    const float* wout = (const float*)d_in[4];
    const float* bout = (const float*)d_in[5];
    float* y = (float*)d_out;

    ushort* wqkvb = (ushort*)d_ws;            // 196608 bf16
    ushort* woutb = wqkvb + 196608;           // 65536 bf16  (total 512 KB of ws)

    lsa_wconv<<<dim3(1024), dim3(256), 0, stream>>>(wqkv, wout, wqkvb);
    lsa_fused<<<dim3(4 * NWIN), dim3(512), 0, stream>>>(x, bqkv, posb, bout, wqkvb, woutb, y);
}